// Round 1
// 273.143 us; speedup vs baseline: 1.1421x; 1.1421x over previous
//
#include <hip/hip_runtime.h>
#include <hip/hip_bf16.h>

typedef __attribute__((ext_vector_type(8))) short short8;
typedef __attribute__((ext_vector_type(4))) float float4v;
typedef __attribute__((ext_vector_type(2))) unsigned int uint2v;

#define MFMA_BF16 __builtin_amdgcn_mfma_f32_16x16x32_bf16

__device__ __forceinline__ unsigned short f2b(float f) {
  union { float f; unsigned u; } v; v.f = f;
  unsigned r = v.u + 0x7FFFu + ((v.u >> 16) & 1u);  // round-to-nearest-even
  return (unsigned short)(r >> 16);
}

__device__ __forceinline__ unsigned pk2(float x, float y) {
  float2 v; v.x = x; v.y = y;
  __hip_bfloat162 h = __float22bfloat162_rn(v);
  union { __hip_bfloat162 h; unsigned u; } c; c.h = h;
  return c.u;
}

// async global->LDS, 16B per lane. LDS dest must be wave-uniform + lane*16.
__device__ __forceinline__ void gld16(const unsigned short* g, unsigned short* l) {
  __builtin_amdgcn_global_load_lds(
      (const __attribute__((address_space(1))) unsigned int*)g,
      (__attribute__((address_space(3))) unsigned int*)l, 16, 0, 0);
}

// Swizzled element index within a [rows][64] bf16 LDS tile.
__device__ __forceinline__ int swa(int r, int k) {
  return (r << 6) + ((((k >> 3) ^ r ^ (r >> 3)) & 7) << 3) + (k & 7);
}

__global__ __launch_bounds__(256) void cast_f32_bf16(const float* __restrict__ src,
                                                     unsigned short* __restrict__ dst,
                                                     int n4) {
  int i = blockIdx.x * 256 + threadIdx.x;
  if (i >= n4) return;
  float4 f = ((const float4*)src)[i];
  uint2 o;
  o.x = pk2(f.x, f.y);
  o.y = pk2(f.z, f.w);
  ((uint2*)dst)[i] = o;
}

__global__ __launch_bounds__(256) void cast_w3(const float* __restrict__ s0,
                                               const float* __restrict__ s1,
                                               const float* __restrict__ s2,
                                               unsigned short* __restrict__ dst) {
  const int z = blockIdx.y;
  const float* src = (z == 0) ? s0 : (z == 1 ? s1 : s2);
  int i = blockIdx.x * 256 + threadIdx.x;
  float4 f = ((const float4*)src)[i];
  uint2 o;
  o.x = pk2(f.x, f.y);
  o.y = pk2(f.z, f.w);
  ((uint2*)(dst + (size_t)z * 589824))[i] = o;
}

// C[m,n] = sum_k X[m,k] * W[n,k] + bias[n], bf16 out. M=16384, N=768 (x3 z).
// z=0 -> Q [token][dim] PRE-SCALED by (1/sqrt(64))*log2(e) so attn's exp2 needs
// no per-element multiply. z=1 -> K. z=2 -> V^T [b][h][d][s].
__global__ __launch_bounds__(256) void qkv_gemm(
    const unsigned short* __restrict__ X, const unsigned short* __restrict__ Wall,
    const float* __restrict__ b0, const float* __restrict__ b1, const float* __restrict__ b2,
    unsigned short* __restrict__ O0, unsigned short* __restrict__ O1, unsigned short* __restrict__ OVT) {
  __shared__ __align__(16) unsigned short Sh[16384];  // As | Bs, reused as T
  unsigned short* As = Sh;
  unsigned short* Bs = Sh + 8192;
  const int z = blockIdx.z;
  const unsigned short* W = Wall + (size_t)z * 589824;
  const float* bias = (z == 0) ? b0 : (z == 1 ? b1 : b2);
  const int m0 = blockIdx.x * 128, n0 = blockIdx.y * 128;
  const int t = threadIdx.x, w = t >> 6, l = t & 63, qd = l >> 4, col = l & 15;
  const int wm = (w & 1) * 64, wn = (w >> 1) * 64;

  float4v acc[4][4];
#pragma unroll
  for (int i = 0; i < 4; ++i)
#pragma unroll
    for (int j = 0; j < 4; ++j) acc[i][j] = (float4v)0.0f;

  const unsigned short* Xp = X + (size_t)m0 * 768;
  const unsigned short* Wp = W + (size_t)n0 * 768;

  for (int k0 = 0; k0 < 768; k0 += 64) {
#pragma unroll
    for (int p = 0; p < 4; ++p) {
      const int c = p * 256 + t;
      const int row = c >> 3;
      const int cc = (c ^ row ^ (row >> 3)) & 7;  // inverse source perm
      gld16(&Xp[(size_t)row * 768 + k0 + cc * 8], &As[c * 8]);
      gld16(&Wp[(size_t)row * 768 + k0 + cc * 8], &Bs[c * 8]);
    }
    __syncthreads();
#pragma unroll
    for (int ks = 0; ks < 2; ++ks) {
      short8 af[4], bf[4];
#pragma unroll
      for (int mi = 0; mi < 4; ++mi)
        af[mi] = *(const short8*)&As[swa(wm + mi * 16 + col, ks * 32 + qd * 8)];
#pragma unroll
      for (int ni = 0; ni < 4; ++ni)
        bf[ni] = *(const short8*)&Bs[swa(wn + ni * 16 + col, ks * 32 + qd * 8)];
#pragma unroll
      for (int mi = 0; mi < 4; ++mi)
#pragma unroll
        for (int ni = 0; ni < 4; ++ni)
          acc[mi][ni] = MFMA_BF16(af[mi], bf[ni], acc[mi][ni], 0, 0, 0);
    }
    __syncthreads();
  }

  if (z < 2) {
    unsigned short* O = (z == 0) ? O0 : O1;
    const float osc = (z == 0) ? 0.18033688f : 1.0f;  // log2(e)/sqrt(64) folded into Q
#pragma unroll
    for (int ni = 0; ni < 4; ++ni) {
      const int n = n0 + wn + ni * 16 + col;
      const float bb = bias[n];
#pragma unroll
      for (int mi = 0; mi < 4; ++mi)
#pragma unroll
        for (int r = 0; r < 4; ++r) {
          const int m = m0 + wm + mi * 16 + qd * 4 + r;
          O[(size_t)m * 768 + n] = f2b((acc[mi][ni][r] + bb) * osc);
        }
    }
  } else {
    // V^T via LDS transpose: T[n_local][m_local], 128x128 ushort in Sh,
    // m-chunk XOR-swizzled (tc = (ml>>3) ^ nl) for conflict-free access.
#pragma unroll
    for (int ni = 0; ni < 4; ++ni) {
      const int nl = wn + ni * 16 + col;
      const float bb = bias[n0 + nl];
#pragma unroll
      for (int mi = 0; mi < 4; ++mi) {
        const int ml = wm + mi * 16 + qd * 4;
        ushort4 o;
        o.x = f2b(acc[mi][ni][0] + bb);
        o.y = f2b(acc[mi][ni][1] + bb);
        o.z = f2b(acc[mi][ni][2] + bb);
        o.w = f2b(acc[mi][ni][3] + bb);
        *(ushort4*)&Sh[(nl << 7) + ((((ml >> 3) ^ nl) & 15) << 3) + (ml & 7)] = o;
      }
    }
    __syncthreads();
    const int nl = t >> 1, mh = (t & 1) * 64;
    const int n = n0 + nl, hh = n >> 6, dd = n & 63;
    unsigned short* dstp =
        &OVT[(((size_t)(m0 >> 10) * 12 + hh) * 64 + dd) * 1024 + (m0 & 1023) + mh];
#pragma unroll
    for (int j = 0; j < 8; ++j) {
      const int mc = (mh >> 3) + j;
      uint4 vv = *(const uint4*)&Sh[(nl << 7) + (((mc ^ nl) & 15) << 3)];
      *(uint4*)&dstp[j * 8] = vv;
    }
  }
}

// Flash attention v6: in-register P transform (cvt_pk + permlane32/16_swap)
// replaces the Pls LDS round-trip; row-sum l via ones-MFMA (no VALU adds, no
// final shuffles); Q pre-scaled in qkv_gemm so softmax is exp2 directly;
// XCD-clustered flat grid so the 8 qt-blocks of one (b,h) share one L2.
// LDS 32 KB, one barrier/kt.
__global__ __launch_bounds__(256) void attn(
    const unsigned short* __restrict__ Q, const unsigned short* __restrict__ K,
    const unsigned short* __restrict__ VT, float* __restrict__ O) {
  __shared__ __align__(16) unsigned short Ks0[4096];
  __shared__ __align__(16) unsigned short Ks1[4096];
  __shared__ __align__(16) unsigned short Vt0[4096];
  __shared__ __align__(16) unsigned short Vt1[4096];

  // XCD-aware remap: xcd = g%8 gets origs [xcd*192, (xcd+1)*192) -> the 8
  // qt-siblings of each (b,h) are consecutive origs on ONE XCD's L2.
  const int g = blockIdx.x;
  const int orig = (g & 7) * 192 + (g >> 3);
  const int qt = orig & 7;
  const int hb = orig >> 3;  // h + 12*b
  const int b = hb / 12;
  const int h = hb - b * 12;

  const int t = threadIdx.x, w = t >> 6, l = t & 63, qd = l >> 4, col = l & 15;
  const size_t bh = (size_t)b * 786432 + (size_t)h * 64;
  const unsigned short* Kb = K + bh;
  const unsigned short* VTb = VT + ((size_t)(b * 12 + h)) * 65536;

  // Q fragments: B-operand layout B[n=q][k=d], direct from global.
  short8 qf[2][2];
  {
    const unsigned short* Qg = Q + bh + (size_t)(qt * 128 + w * 32) * 768;
#pragma unroll
    for (int mi = 0; mi < 2; ++mi)
#pragma unroll
      for (int ks = 0; ks < 2; ++ks)
        qf[mi][ks] =
            *(const short8*)&Qg[(size_t)(mi * 16 + col) * 768 + ks * 32 + qd * 8];
  }

  const int c0 = t, c1 = 256 + t;
  const int r0 = c0 >> 3, cc0 = (c0 ^ r0 ^ (r0 >> 3)) & 7;
  const int r1 = c1 >> 3, cc1 = (c1 ^ r1 ^ (r1 >> 3)) & 7;

#define STAGE_K(ktile, dst)                                             \
  do {                                                                  \
    const unsigned short* Kg_ = Kb + (size_t)(ktile)*49152;             \
    gld16(&Kg_[(size_t)r0 * 768 + cc0 * 8], &dst[c0 * 8]);              \
    gld16(&Kg_[(size_t)r1 * 768 + cc1 * 8], &dst[c1 * 8]);              \
  } while (0)

#define STAGE_V(ktile, dst)                                             \
  do {                                                                  \
    const unsigned short* Vg_ = VTb + (ktile)*64;                       \
    gld16(&Vg_[(size_t)r0 * 1024 + cc0 * 8], &dst[c0 * 8]);             \
    gld16(&Vg_[(size_t)r1 * 1024 + cc1 * 8], &dst[c1 * 8]);             \
  } while (0)

  STAGE_K(0, Ks0);
  STAGE_V(0, Vt0);

  float4v acc[2][4];
  float4v accl[2];
#pragma unroll
  for (int mi = 0; mi < 2; ++mi) {
    accl[mi] = (float4v)0.0f;
#pragma unroll
    for (int dt = 0; dt < 4; ++dt) acc[mi][dt] = (float4v)0.0f;
  }

  short8 ones;
#pragma unroll
  for (int j = 0; j < 8; ++j) ones[j] = (short)0x3F80;  // bf16 1.0

  __syncthreads();

#define ATTN_ITER(kt, KsR, VtR, KsW, VtW)                                 \
  do {                                                                    \
    if ((kt) < 15) {                                                      \
      STAGE_K((kt) + 1, KsW);                                             \
      STAGE_V((kt) + 1, VtW);                                             \
    }                                                                     \
    short8 kf[2][4];                                                      \
    _Pragma("unroll") for (int ks = 0; ks < 2; ++ks)                      \
        _Pragma("unroll") for (int ni = 0; ni < 4; ++ni)                  \
        kf[ks][ni] =                                                      \
        *(const short8*)&KsR[swa(ni * 16 + col, ks * 32 + qd * 8)];       \
    float4v sT[2][4];                                                     \
    _Pragma("unroll") for (int mi = 0; mi < 2; ++mi)                      \
        _Pragma("unroll") for (int ni = 0; ni < 4; ++ni)                  \
        sT[mi][ni] = (float4v)0.0f;                                       \
    _Pragma("unroll") for (int ks = 0; ks < 2; ++ks)                      \
        _Pragma("unroll") for (int ni = 0; ni < 4; ++ni) {                \
      sT[0][ni] = MFMA_BF16(kf[ks][ni], qf[0][ks], sT[0][ni], 0, 0, 0);   \
      sT[1][ni] = MFMA_BF16(kf[ks][ni], qf[1][ks], sT[1][ni], 0, 0, 0);   \
    }                                                                     \
    _Pragma("unroll") for (int s = 0; s < 2; ++s) {                       \
      short8 pf[2];                                                       \
      _Pragma("unroll") for (int mi = 0; mi < 2; ++mi) {                  \
        float4v sa = sT[mi][s * 2 + 0];                                   \
        float4v sb = sT[mi][s * 2 + 1];                                   \
        unsigned A0 = pk2(__builtin_amdgcn_exp2f(sa[0]),                  \
                          __builtin_amdgcn_exp2f(sa[1]));                 \
        unsigned A1 = pk2(__builtin_amdgcn_exp2f(sa[2]),                  \
                          __builtin_amdgcn_exp2f(sa[3]));                 \
        unsigned B0 = pk2(__builtin_amdgcn_exp2f(sb[0]),                  \
                          __builtin_amdgcn_exp2f(sb[1]));                 \
        unsigned B1 = pk2(__builtin_amdgcn_exp2f(sb[2]),                  \
                          __builtin_amdgcn_exp2f(sb[3]));                 \
        /* acc rows qd*4+{0..3} -> B-frag rows qd*8+{0..7}: 32swap, 16swap */ \
        uint2v x0 = __builtin_amdgcn_permlane32_swap(A0, B0, false, false);   \
        uint2v x1 = __builtin_amdgcn_permlane32_swap(A1, B1, false, false);   \
        uint2v y02 = __builtin_amdgcn_permlane16_swap(x0[0], x0[1], false, false); \
        uint2v y13 = __builtin_amdgcn_permlane16_swap(x1[0], x1[1], false, false); \
        union { unsigned u[4]; short8 v; } pu;                            \
        pu.u[0] = y02[0]; pu.u[1] = y13[0];                               \
        pu.u[2] = y02[1]; pu.u[3] = y13[1];                               \
        pf[mi] = pu.v;                                                    \
      }                                                                   \
      const int kk = s * 32 + qd * 8;                                     \
      _Pragma("unroll") for (int dt = 0; dt < 4; ++dt) {                  \
        short8 vf = *(const short8*)&VtR[swa(dt * 16 + col, kk)];         \
        acc[0][dt] = MFMA_BF16(vf, pf[0], acc[0][dt], 0, 0, 0);           \
        acc[1][dt] = MFMA_BF16(vf, pf[1], acc[1][dt], 0, 0, 0);           \
      }                                                                   \
      accl[0] = MFMA_BF16(ones, pf[0], accl[0], 0, 0, 0);                 \
      accl[1] = MFMA_BF16(ones, pf[1], accl[1], 0, 0, 0);                 \
    }                                                                     \
    __syncthreads();                                                      \
  } while (0)

  for (int kt2 = 0; kt2 < 16; kt2 += 2) {
    ATTN_ITER(kt2, Ks0, Vt0, Ks1, Vt1);
    ATTN_ITER(kt2 + 1, Ks1, Vt1, Ks0, Vt0);
  }

  float* Og = O + (size_t)(b * 1024 + qt * 128) * 768 + h * 64;
#pragma unroll
  for (int mi = 0; mi < 2; ++mi) {
    const float rl = 1.0f / accl[mi][0];  // ones-MFMA: every row holds full sum
    const int q = w * 32 + mi * 16 + col;
#pragma unroll
    for (int dt = 0; dt < 4; ++dt) {
      float4 o;
      o.x = acc[mi][dt][0] * rl;
      o.y = acc[mi][dt][1] * rl;
      o.z = acc[mi][dt][2] * rl;
      o.w = acc[mi][dt][3] * rl;
      *(float4*)&Og[(size_t)q * 768 + dt * 16 + qd * 4] = o;
    }
  }
#undef STAGE_K
#undef STAGE_V
#undef ATTN_ITER
}

extern "C" void kernel_launch(void* const* d_in, const int* in_sizes, int n_in,
                              void* d_out, int out_size, void* d_ws, size_t ws_size,
                              hipStream_t stream) {
  const float* hs = (const float*)d_in[0];
  const float* Wq = (const float*)d_in[1];
  const float* bq = (const float*)d_in[2];
  const float* Wk = (const float*)d_in[3];
  const float* bk = (const float*)d_in[4];
  const float* Wv = (const float*)d_in[5];
  const float* bv = (const float*)d_in[6];
  float* out = (float*)d_out;
  char* ws = (char*)d_ws;

  unsigned short* Xb = (unsigned short*)ws;
  unsigned short* Wb = (unsigned short*)(ws + 25165824);
  unsigned short* Qb = (unsigned short*)(ws + 28704768);
  unsigned short* Kb = (unsigned short*)(ws + 53870592);
  unsigned short* Vb = (unsigned short*)(ws + 79036416);  // V^T [b][h][d][s]

  cast_f32_bf16<<<12288, 256, 0, stream>>>(hs, Xb, 3145728);
  cast_w3<<<dim3(576, 3), 256, 0, stream>>>(Wq, Wk, Wv, Wb);

  qkv_gemm<<<dim3(128, 6, 3), 256, 0, stream>>>(Xb, Wb, bq, bk, bv, Qb, Kb, Vb);

  attn<<<dim3(1536), 256, 0, stream>>>(Qb, Kb, Vb, out);
}

// Round 2
// 259.680 us; speedup vs baseline: 1.2014x; 1.0518x over previous
//
#include <hip/hip_runtime.h>
#include <hip/hip_bf16.h>

typedef __attribute__((ext_vector_type(8))) short short8;
typedef __attribute__((ext_vector_type(4))) float float4v;
typedef __attribute__((ext_vector_type(2))) unsigned int uint2v;

#define MFMA_BF16 __builtin_amdgcn_mfma_f32_16x16x32_bf16

__device__ __forceinline__ unsigned short f2b(float f) {
  union { float f; unsigned u; } v; v.f = f;
  unsigned r = v.u + 0x7FFFu + ((v.u >> 16) & 1u);  // round-to-nearest-even
  return (unsigned short)(r >> 16);
}

__device__ __forceinline__ unsigned pk2(float x, float y) {
  float2 v; v.x = x; v.y = y;
  __hip_bfloat162 h = __float22bfloat162_rn(v);
  union { __hip_bfloat162 h; unsigned u; } c; c.h = h;
  return c.u;
}

// async global->LDS, 16B per lane. LDS dest must be wave-uniform + lane*16.
__device__ __forceinline__ void gld16(const unsigned short* g, unsigned short* l) {
  __builtin_amdgcn_global_load_lds(
      (const __attribute__((address_space(1))) unsigned int*)g,
      (__attribute__((address_space(3))) unsigned int*)l, 16, 0, 0);
}

// Swizzled element index within a [rows][64] bf16 LDS tile.
__device__ __forceinline__ int swa(int r, int k) {
  return (r << 6) + ((((k >> 3) ^ r ^ (r >> 3)) & 7) << 3) + (k & 7);
}

// Fused cast: hs (12288 blocks) + Wq/Wk/Wv (576 blocks each) in one launch.
__global__ __launch_bounds__(256) void cast_all(
    const float* __restrict__ hs, const float* __restrict__ Wq,
    const float* __restrict__ Wk, const float* __restrict__ Wv,
    unsigned short* __restrict__ Xb, unsigned short* __restrict__ Wb) {
  const int blk = blockIdx.x;
  const float* src;
  unsigned short* dst;
  int i;
  if (blk < 12288) {
    i = blk * 256 + threadIdx.x;
    src = hs;
    dst = Xb;
  } else {
    const int x = blk - 12288;       // 0..1727
    const int z = x / 576;           // 0,1,2
    i = (x - z * 576) * 256 + threadIdx.x;
    src = (z == 0) ? Wq : (z == 1 ? Wk : Wv);
    dst = Wb + (size_t)z * 589824;
  }
  float4 f = ((const float4*)src)[i];
  uint2 o;
  o.x = pk2(f.x, f.y);
  o.y = pk2(f.z, f.w);
  ((uint2*)dst)[i] = o;
}

// QKV GEMM v2: C[m,n'] = sum_k X[m,k]*Wall[n',k] + bias, n' in [0,2304) spans
// Q|K|V. BM=256 BN=128 BK=64, 8 waves (4M x 2N), per-wave 64x64 out.
// TRIPLE-buffered LDS (144 KB dynamic, 1 block/CU), prefetch depth 2:
// STAGE(t+2) issued at tile-t top; per-tile counted s_waitcnt vmcnt(6)
// (= loads/tile) proves tile t+1 resident while t+2's loads stay in flight.
// Raw s_barrier (no vmcnt(0) drain) once per tile. T5 setprio around MFMA.
// z=0 output pre-scaled by log2(e)/sqrt(64); z=2 transposed to [b][h][d][s].
__global__ __launch_bounds__(512) void qkv_gemm(
    const unsigned short* __restrict__ X, const unsigned short* __restrict__ Wall,
    const float* __restrict__ b0, const float* __restrict__ b1, const float* __restrict__ b2,
    unsigned short* __restrict__ O0, unsigned short* __restrict__ O1, unsigned short* __restrict__ OVT) {
  extern __shared__ __align__(16) unsigned short LDS[];  // 3 * (16384 A + 8192 B)

  // XCD swizzle: xcd g&7 owns origs [xcd*144,+144) = 8 m-blocks x 18 n-blocks.
  const int g = blockIdx.x;
  const int orig = (g & 7) * 144 + (g >> 3);
  const int mblk = orig / 18;
  const int nblk = orig - mblk * 18;
  const int m0 = mblk * 256, n0p = nblk * 128;

  const int t = threadIdx.x, w = t >> 6, l = t & 63, qd = l >> 4, col = l & 15;
  const int wm64 = (w & 3) * 64, wn64 = (w >> 2) * 64;
  const int qd8 = qd * 8;

  // Per-thread staging slots: A tile 2048 chunks (4 loads), B tile 1024 (2).
  const int cA0 = t, cA1 = 512 + t, cA2 = 1024 + t, cA3 = 1536 + t;
  const int rA0 = cA0 >> 3, rA1 = cA1 >> 3, rA2 = cA2 >> 3, rA3 = cA3 >> 3;
  const int pA0 = (cA0 ^ rA0 ^ (rA0 >> 3)) & 7, pA1 = (cA1 ^ rA1 ^ (rA1 >> 3)) & 7;
  const int pA2 = (cA2 ^ rA2 ^ (rA2 >> 3)) & 7, pA3 = (cA3 ^ rA3 ^ (rA3 >> 3)) & 7;
  const int cB0 = t, cB1 = 512 + t;
  const int rB0 = cB0 >> 3, rB1 = cB1 >> 3;
  const int pB0 = (cB0 ^ rB0 ^ (rB0 >> 3)) & 7, pB1 = (cB1 ^ rB1 ^ (rB1 >> 3)) & 7;

  const unsigned short* Xa0 = X + (size_t)(m0 + rA0) * 768 + pA0 * 8;
  const unsigned short* Xa1 = X + (size_t)(m0 + rA1) * 768 + pA1 * 8;
  const unsigned short* Xa2 = X + (size_t)(m0 + rA2) * 768 + pA2 * 8;
  const unsigned short* Xa3 = X + (size_t)(m0 + rA3) * 768 + pA3 * 8;
  const unsigned short* Wb0 = Wall + (size_t)(n0p + rB0) * 768 + pB0 * 8;
  const unsigned short* Wb1 = Wall + (size_t)(n0p + rB1) * 768 + pB1 * 8;
  const int dA0 = cA0 * 8, dA1 = cA1 * 8, dA2 = cA2 * 8, dA3 = cA3 * 8;
  const int dB0 = cB0 * 8, dB1 = cB1 * 8;

#define STAGE(kt, sb)                                         \
  do {                                                        \
    unsigned short* SA_ = LDS + (sb)*24576;                   \
    unsigned short* SB_ = SA_ + 16384;                        \
    const int kk_ = (kt)*64;                                  \
    gld16(Xa0 + kk_, SA_ + dA0);                              \
    gld16(Xa1 + kk_, SA_ + dA1);                              \
    gld16(Xa2 + kk_, SA_ + dA2);                              \
    gld16(Xa3 + kk_, SA_ + dA3);                              \
    gld16(Wb0 + kk_, SB_ + dB0);                              \
    gld16(Wb1 + kk_, SB_ + dB1);                              \
  } while (0)

  float4v acc[4][4];
#pragma unroll
  for (int i = 0; i < 4; ++i)
#pragma unroll
    for (int j = 0; j < 4; ++j) acc[i][j] = (float4v)0.0f;

#define COMPUTE(cur)                                                          \
  do {                                                                        \
    const unsigned short* Ar_ = LDS + (cur)*24576;                            \
    const unsigned short* Br_ = Ar_ + 16384;                                  \
    _Pragma("unroll") for (int ks = 0; ks < 2; ++ks) {                        \
      short8 af[4], bf[4];                                                    \
      _Pragma("unroll") for (int mi = 0; mi < 4; ++mi)                        \
          af[mi] = *(const short8*)&Ar_[swa(wm64 + mi * 16 + col,             \
                                            ks * 32 + qd8)];                  \
      _Pragma("unroll") for (int ni = 0; ni < 4; ++ni)                        \
          bf[ni] = *(const short8*)&Br_[swa(wn64 + ni * 16 + col,             \
                                            ks * 32 + qd8)];                  \
      __builtin_amdgcn_s_setprio(1);                                          \
      _Pragma("unroll") for (int mi = 0; mi < 4; ++mi)                        \
          _Pragma("unroll") for (int ni = 0; ni < 4; ++ni)                    \
          acc[mi][ni] = MFMA_BF16(af[mi], bf[ni], acc[mi][ni], 0, 0, 0);      \
      __builtin_amdgcn_s_setprio(0);                                          \
    }                                                                         \
  } while (0)

  // Prologue: stage tiles 0,1; wait tile 0 (6 newest = tile 1 may fly).
  STAGE(0, 0);
  STAGE(1, 1);
  asm volatile("s_waitcnt vmcnt(6)" ::: "memory");
  __builtin_amdgcn_s_barrier();
  __builtin_amdgcn_sched_barrier(0);

  int cur = 0;
#pragma unroll 1
  for (int kt = 0; kt < 10; ++kt) {
    const int sb = (cur == 0) ? 2 : cur - 1;  // (cur+2)%3
    STAGE(kt + 2, sb);
    COMPUTE(cur);
    // tile kt+1's 6 loads complete; tile kt+2's 6 may remain in flight.
    asm volatile("s_waitcnt vmcnt(6)" ::: "memory");
    __builtin_amdgcn_s_barrier();
    __builtin_amdgcn_sched_barrier(0);
    cur = (cur == 2) ? 0 : cur + 1;
  }
  COMPUTE(cur);  // tile 10
  asm volatile("s_waitcnt vmcnt(0)" ::: "memory");
  __builtin_amdgcn_s_barrier();
  __builtin_amdgcn_sched_barrier(0);
  cur = (cur == 2) ? 0 : cur + 1;
  COMPUTE(cur);  // tile 11

  const int zz = n0p / 768;          // uniform per block
  const int nbase = n0p - zz * 768;  // local n within z

  if (zz < 2) {
    unsigned short* O = (zz == 0) ? O0 : O1;
    const float* bias = (zz == 0) ? b0 : b1;
    const float osc = (zz == 0) ? 0.18033688f : 1.0f;  // log2(e)/sqrt(64) into Q
#pragma unroll
    for (int ni = 0; ni < 4; ++ni) {
      const int n = nbase + wn64 + ni * 16 + col;
      const float bb = bias[n];
#pragma unroll
      for (int mi = 0; mi < 4; ++mi)
#pragma unroll
        for (int r = 0; r < 4; ++r) {
          const int m = m0 + wm64 + mi * 16 + qd * 4 + r;
          O[(size_t)m * 768 + n] = f2b((acc[mi][ni][r] + bb) * osc);
        }
    }
  } else {
    // V^T via LDS transpose: T[nl][ml] 128x256 ushort, chunk XOR-swizzled.
    __syncthreads();  // all waves done with k-loop LDS
    unsigned short* T = LDS;
#pragma unroll
    for (int ni = 0; ni < 4; ++ni) {
      const int nl = wn64 + ni * 16 + col;
      const float bb = b2[nbase + nl];
#pragma unroll
      for (int mi = 0; mi < 4; ++mi) {
        const int ml = wm64 + mi * 16 + qd * 4;
        const int mc = ml >> 3;
        ushort4 o;
        o.x = f2b(acc[mi][ni][0] + bb);
        o.y = f2b(acc[mi][ni][1] + bb);
        o.z = f2b(acc[mi][ni][2] + bb);
        o.w = f2b(acc[mi][ni][3] + bb);
        *(ushort4*)&T[(nl << 8) + (((mc ^ (nl & 31)) & 31) << 3) + (ml & 7)] = o;
      }
    }
    __syncthreads();
    const int nl2 = t >> 2;        // 0..127
    const int seg = t & 3;         // 0..3 (64 m each)
    const int nglob = nbase + nl2; // 0..767
    const int hh = nglob >> 6, dd = nglob & 63;
    const int bb2 = m0 >> 10;
    unsigned short* dstp =
        &OVT[(((size_t)bb2 * 12 + hh) * 64 + dd) * 1024 + (m0 & 1023) + seg * 64];
#pragma unroll
    for (int j = 0; j < 8; ++j) {
      const int mc = seg * 8 + j;
      uint4 vv = *(const uint4*)&T[(nl2 << 8) + (((mc ^ (nl2 & 31)) & 31) << 3)];
      *(uint4*)&dstp[j * 8] = vv;
    }
  }
#undef STAGE
#undef COMPUTE
}

// Flash attention v6: in-register P transform (cvt_pk + permlane32/16_swap),
// row-sum l via ones-MFMA, Q pre-scaled, XCD-clustered flat grid. LDS 32 KB.
__global__ __launch_bounds__(256) void attn(
    const unsigned short* __restrict__ Q, const unsigned short* __restrict__ K,
    const unsigned short* __restrict__ VT, float* __restrict__ O) {
  __shared__ __align__(16) unsigned short Ks0[4096];
  __shared__ __align__(16) unsigned short Ks1[4096];
  __shared__ __align__(16) unsigned short Vt0[4096];
  __shared__ __align__(16) unsigned short Vt1[4096];

  const int g = blockIdx.x;
  const int orig = (g & 7) * 192 + (g >> 3);
  const int qt = orig & 7;
  const int hb = orig >> 3;  // h + 12*b
  const int b = hb / 12;
  const int h = hb - b * 12;

  const int t = threadIdx.x, w = t >> 6, l = t & 63, qd = l >> 4, col = l & 15;
  const size_t bh = (size_t)b * 786432 + (size_t)h * 64;
  const unsigned short* Kb = K + bh;
  const unsigned short* VTb = VT + ((size_t)(b * 12 + h)) * 65536;

  short8 qf[2][2];
  {
    const unsigned short* Qg = Q + bh + (size_t)(qt * 128 + w * 32) * 768;
#pragma unroll
    for (int mi = 0; mi < 2; ++mi)
#pragma unroll
      for (int ks = 0; ks < 2; ++ks)
        qf[mi][ks] =
            *(const short8*)&Qg[(size_t)(mi * 16 + col) * 768 + ks * 32 + qd * 8];
  }

  const int c0 = t, c1 = 256 + t;
  const int r0 = c0 >> 3, cc0 = (c0 ^ r0 ^ (r0 >> 3)) & 7;
  const int r1 = c1 >> 3, cc1 = (c1 ^ r1 ^ (r1 >> 3)) & 7;

#define STAGE_K(ktile, dst)                                             \
  do {                                                                  \
    const unsigned short* Kg_ = Kb + (size_t)(ktile)*49152;             \
    gld16(&Kg_[(size_t)r0 * 768 + cc0 * 8], &dst[c0 * 8]);              \
    gld16(&Kg_[(size_t)r1 * 768 + cc1 * 8], &dst[c1 * 8]);              \
  } while (0)

#define STAGE_V(ktile, dst)                                             \
  do {                                                                  \
    const unsigned short* Vg_ = VTb + (ktile)*64;                       \
    gld16(&Vg_[(size_t)r0 * 1024 + cc0 * 8], &dst[c0 * 8]);             \
    gld16(&Vg_[(size_t)r1 * 1024 + cc1 * 8], &dst[c1 * 8]);             \
  } while (0)

  STAGE_K(0, Ks0);
  STAGE_V(0, Vt0);

  float4v acc[2][4];
  float4v accl[2];
#pragma unroll
  for (int mi = 0; mi < 2; ++mi) {
    accl[mi] = (float4v)0.0f;
#pragma unroll
    for (int dt = 0; dt < 4; ++dt) acc[mi][dt] = (float4v)0.0f;
  }

  short8 ones;
#pragma unroll
  for (int j = 0; j < 8; ++j) ones[j] = (short)0x3F80;  // bf16 1.0

  __syncthreads();

#define ATTN_ITER(kt, KsR, VtR, KsW, VtW)                                 \
  do {                                                                    \
    if ((kt) < 15) {                                                      \
      STAGE_K((kt) + 1, KsW);                                             \
      STAGE_V((kt) + 1, VtW);                                             \
    }                                                                     \
    short8 kf[2][4];                                                      \
    _Pragma("unroll") for (int ks = 0; ks < 2; ++ks)                      \
        _Pragma("unroll") for (int ni = 0; ni < 4; ++ni)                  \
        kf[ks][ni] =                                                      \
        *(const short8*)&KsR[swa(ni * 16 + col, ks * 32 + qd * 8)];       \
    float4v sT[2][4];                                                     \
    _Pragma("unroll") for (int mi = 0; mi < 2; ++mi)                      \
        _Pragma("unroll") for (int ni = 0; ni < 4; ++ni)                  \
        sT[mi][ni] = (float4v)0.0f;                                       \
    _Pragma("unroll") for (int ks = 0; ks < 2; ++ks)                      \
        _Pragma("unroll") for (int ni = 0; ni < 4; ++ni) {                \
      sT[0][ni] = MFMA_BF16(kf[ks][ni], qf[0][ks], sT[0][ni], 0, 0, 0);   \
      sT[1][ni] = MFMA_BF16(kf[ks][ni], qf[1][ks], sT[1][ni], 0, 0, 0);   \
    }                                                                     \
    _Pragma("unroll") for (int s = 0; s < 2; ++s) {                       \
      short8 pf[2];                                                       \
      _Pragma("unroll") for (int mi = 0; mi < 2; ++mi) {                  \
        float4v sa = sT[mi][s * 2 + 0];                                   \
        float4v sb = sT[mi][s * 2 + 1];                                   \
        unsigned A0 = pk2(__builtin_amdgcn_exp2f(sa[0]),                  \
                          __builtin_amdgcn_exp2f(sa[1]));                 \
        unsigned A1 = pk2(__builtin_amdgcn_exp2f(sa[2]),                  \
                          __builtin_amdgcn_exp2f(sa[3]));                 \
        unsigned B0 = pk2(__builtin_amdgcn_exp2f(sb[0]),                  \
                          __builtin_amdgcn_exp2f(sb[1]));                 \
        unsigned B1 = pk2(__builtin_amdgcn_exp2f(sb[2]),                  \
                          __builtin_amdgcn_exp2f(sb[3]));                 \
        uint2v x0 = __builtin_amdgcn_permlane32_swap(A0, B0, false, false);   \
        uint2v x1 = __builtin_amdgcn_permlane32_swap(A1, B1, false, false);   \
        uint2v y02 = __builtin_amdgcn_permlane16_swap(x0[0], x0[1], false, false); \
        uint2v y13 = __builtin_amdgcn_permlane16_swap(x1[0], x1[1], false, false); \
        union { unsigned u[4]; short8 v; } pu;                            \
        pu.u[0] = y02[0]; pu.u[1] = y13[0];                               \
        pu.u[2] = y02[1]; pu.u[3] = y13[1];                               \
        pf[mi] = pu.v;                                                    \
      }                                                                   \
      const int kk = s * 32 + qd * 8;                                     \
      _Pragma("unroll") for (int dt = 0; dt < 4; ++dt) {                  \
        short8 vf = *(const short8*)&VtR[swa(dt * 16 + col, kk)];         \
        acc[0][dt] = MFMA_BF16(vf, pf[0], acc[0][dt], 0, 0, 0);           \
        acc[1][dt] = MFMA_BF16(vf, pf[1], acc[1][dt], 0, 0, 0);           \
      }                                                                   \
      accl[0] = MFMA_BF16(ones, pf[0], accl[0], 0, 0, 0);                 \
      accl[1] = MFMA_BF16(ones, pf[1], accl[1], 0, 0, 0);                 \
    }                                                                     \
    __syncthreads();                                                      \
  } while (0)

  for (int kt2 = 0; kt2 < 16; kt2 += 2) {
    ATTN_ITER(kt2, Ks0, Vt0, Ks1, Vt1);
    ATTN_ITER(kt2 + 1, Ks1, Vt1, Ks0, Vt0);
  }

  float* Og = O + (size_t)(b * 1024 + qt * 128) * 768 + h * 64;
#pragma unroll
  for (int mi = 0; mi < 2; ++mi) {
    const float rl = 1.0f / accl[mi][0];
    const int q = w * 32 + mi * 16 + col;
#pragma unroll
    for (int dt = 0; dt < 4; ++dt) {
      float4 o;
      o.x = acc[mi][dt][0] * rl;
      o.y = acc[mi][dt][1] * rl;
      o.z = acc[mi][dt][2] * rl;
      o.w = acc[mi][dt][3] * rl;
      *(float4*)&Og[(size_t)q * 768 + dt * 16 + qd * 4] = o;
    }
  }
#undef STAGE_K
#undef STAGE_V
#undef ATTN_ITER
}

extern "C" void kernel_launch(void* const* d_in, const int* in_sizes, int n_in,
                              void* d_out, int out_size, void* d_ws, size_t ws_size,
                              hipStream_t stream) {
  const float* hs = (const float*)d_in[0];
  const float* Wq = (const float*)d_in[1];
  const float* bq = (const float*)d_in[2];
  const float* Wk = (const float*)d_in[3];
  const float* bk = (const float*)d_in[4];
  const float* Wv = (const float*)d_in[5];
  const float* bv = (const float*)d_in[6];
  float* out = (float*)d_out;
  char* ws = (char*)d_ws;

  unsigned short* Xb = (unsigned short*)ws;
  unsigned short* Wb = (unsigned short*)(ws + 25165824);
  unsigned short* Qb = (unsigned short*)(ws + 28704768);
  unsigned short* Kb = (unsigned short*)(ws + 53870592);
  unsigned short* Vb = (unsigned short*)(ws + 79036416);  // V^T [b][h][d][s]

  static bool attr_set = false;
  if (!attr_set) {
    hipFuncSetAttribute((const void*)qkv_gemm,
                        hipFuncAttributeMaxDynamicSharedMemorySize, 147456);
    attr_set = true;
  }

  cast_all<<<14016, 256, 0, stream>>>(hs, Wq, Wk, Wv, Xb, Wb);

  qkv_gemm<<<dim3(1152), 512, 147456, stream>>>(Xb, Wb, bq, bk, bv, Qb, Kb, Vb);

  attn<<<dim3(1536), 256, 0, stream>>>(Qb, Kb, Vb, out);
}

// Round 3
// 257.914 us; speedup vs baseline: 1.2096x; 1.0068x over previous
//
#include <hip/hip_runtime.h>
#include <hip/hip_bf16.h>

typedef __attribute__((ext_vector_type(8))) short short8;
typedef __attribute__((ext_vector_type(4))) float float4v;
typedef __attribute__((ext_vector_type(2))) unsigned int uint2v;

#define MFMA_BF16 __builtin_amdgcn_mfma_f32_16x16x32_bf16

__device__ __forceinline__ unsigned short f2b(float f) {
  union { float f; unsigned u; } v; v.f = f;
  unsigned r = v.u + 0x7FFFu + ((v.u >> 16) & 1u);  // round-to-nearest-even
  return (unsigned short)(r >> 16);
}

__device__ __forceinline__ unsigned pk2(float x, float y) {
  float2 v; v.x = x; v.y = y;
  __hip_bfloat162 h = __float22bfloat162_rn(v);
  union { __hip_bfloat162 h; unsigned u; } c; c.h = h;
  return c.u;
}

// async global->LDS, 16B per lane. LDS dest must be wave-uniform + lane*16.
__device__ __forceinline__ void gld16(const unsigned short* g, unsigned short* l) {
  __builtin_amdgcn_global_load_lds(
      (const __attribute__((address_space(1))) unsigned int*)g,
      (__attribute__((address_space(3))) unsigned int*)l, 16, 0, 0);
}

// Swizzled element index within a [rows][64] bf16 LDS tile.
__device__ __forceinline__ int swa(int r, int k) {
  return (r << 6) + ((((k >> 3) ^ r ^ (r >> 3)) & 7) << 3) + (k & 7);
}

// Fused cast: hs (12288 blocks) + Wq/Wk/Wv (576 blocks each) in one launch.
__global__ __launch_bounds__(256) void cast_all(
    const float* __restrict__ hs, const float* __restrict__ Wq,
    const float* __restrict__ Wk, const float* __restrict__ Wv,
    unsigned short* __restrict__ Xb, unsigned short* __restrict__ Wb) {
  const int blk = blockIdx.x;
  const float* src;
  unsigned short* dst;
  int i;
  if (blk < 12288) {
    i = blk * 256 + threadIdx.x;
    src = hs;
    dst = Xb;
  } else {
    const int x = blk - 12288;       // 0..1727
    const int z = x / 576;           // 0,1,2
    i = (x - z * 576) * 256 + threadIdx.x;
    src = (z == 0) ? Wq : (z == 1 ? Wk : Wv);
    dst = Wb + (size_t)z * 589824;
  }
  float4 f = ((const float4*)src)[i];
  uint2 o;
  o.x = pk2(f.x, f.y);
  o.y = pk2(f.z, f.w);
  ((uint2*)dst)[i] = o;
}

// QKV GEMM v3: C[m,n'] = sum_k X[m,k]*Wall[n',k] + bias, n' in [0,2304).
// BM=256 BN=256 BK=64, 8 waves (2M x 4N), per-wave 128x64 out (acc 8x4).
// Per BK-tile: 2458 MFMA-cy/CU vs one barrier + 64KB stage -> 2x arithmetic
// intensity per sync vs v2. Double-buffered 128 KB dynamic LDS, raw s_barrier
// + vmcnt wait (loads for t+1 issued a full compute phase (~2.5K cy) before
// the wait -> latency fully hidden). Grid 576 (2.25 blk/CU), XCD-swizzled:
// each XCD owns 72 consecutive origs = 8 m-rows x 9 n -> X panel L2-resident.
// z=0 out pre-scaled by log2(e)/sqrt(64); z=2 transposed to [b][h][d][s].
__global__ __launch_bounds__(512, 2) void qkv_gemm(
    const unsigned short* __restrict__ X, const unsigned short* __restrict__ Wall,
    const float* __restrict__ b0, const float* __restrict__ b1, const float* __restrict__ b2,
    unsigned short* __restrict__ O0, unsigned short* __restrict__ O1, unsigned short* __restrict__ OVT) {
  extern __shared__ __align__(16) unsigned short LDS[];  // 2 * (16384 A + 16384 B)

  const int g = blockIdx.x;
  const int orig = (g & 7) * 72 + (g >> 3);
  const int mblk = orig / 9;
  const int nblk = orig - mblk * 9;
  const int m0 = mblk * 256, n0p = nblk * 256;

  const int t = threadIdx.x, w = t >> 6, l = t & 63, qd = l >> 4, col = l & 15;
  const int wm = (w >> 2) * 128, wn = (w & 3) * 64;
  const int qd8 = qd * 8;

  // Staging: A and B tiles are each 2048 16B-chunks; 4 chunks per thread each.
  // Chunk c: row = c>>3 (0..255), perm = inverse source swizzle.
  int rr[4], pp[4];
#pragma unroll
  for (int i = 0; i < 4; ++i) {
    const int c = i * 512 + t;
    const int r = c >> 3;
    rr[i] = r;
    pp[i] = (c ^ r ^ (r >> 3)) & 7;
  }
  const unsigned short* Xbase = X + (size_t)m0 * 768;
  const unsigned short* Wbase = Wall + (size_t)n0p * 768;

#define STAGE(kt, buf)                                                        \
  do {                                                                        \
    unsigned short* SA_ = LDS + (buf)*32768;                                  \
    unsigned short* SB_ = SA_ + 16384;                                        \
    const int kk_ = (kt)*64;                                                  \
    _Pragma("unroll") for (int i = 0; i < 4; ++i)                             \
        gld16(Xbase + (size_t)rr[i] * 768 + kk_ + pp[i] * 8,                  \
              SA_ + (i * 512 + t) * 8);                                       \
    _Pragma("unroll") for (int i = 0; i < 4; ++i)                             \
        gld16(Wbase + (size_t)rr[i] * 768 + kk_ + pp[i] * 8,                  \
              SB_ + (i * 512 + t) * 8);                                       \
  } while (0)

  float4v acc[8][4];
#pragma unroll
  for (int i = 0; i < 8; ++i)
#pragma unroll
    for (int j = 0; j < 4; ++j) acc[i][j] = (float4v)0.0f;

#define COMPUTE(buf)                                                          \
  do {                                                                        \
    const unsigned short* Ar_ = LDS + (buf)*32768;                            \
    const unsigned short* Br_ = Ar_ + 16384;                                  \
    _Pragma("unroll") for (int ks = 0; ks < 2; ++ks) {                        \
      short8 af[8], bf[4];                                                    \
      _Pragma("unroll") for (int mi = 0; mi < 8; ++mi)                        \
          af[mi] = *(const short8*)&Ar_[swa(wm + mi * 16 + col,               \
                                            ks * 32 + qd8)];                  \
      _Pragma("unroll") for (int ni = 0; ni < 4; ++ni)                        \
          bf[ni] = *(const short8*)&Br_[swa(wn + ni * 16 + col,               \
                                            ks * 32 + qd8)];                  \
      __builtin_amdgcn_s_setprio(1);                                          \
      _Pragma("unroll") for (int mi = 0; mi < 8; ++mi)                        \
          _Pragma("unroll") for (int ni = 0; ni < 4; ++ni)                    \
          acc[mi][ni] = MFMA_BF16(af[mi], bf[ni], acc[mi][ni], 0, 0, 0);      \
      __builtin_amdgcn_s_setprio(0);                                          \
    }                                                                         \
  } while (0)

  STAGE(0, 0);
  asm volatile("s_waitcnt vmcnt(0)" ::: "memory");
  __builtin_amdgcn_s_barrier();
  __builtin_amdgcn_sched_barrier(0);

  int cur = 0;
#pragma unroll 1
  for (int kt = 0; kt < 11; ++kt) {
    STAGE(kt + 1, cur ^ 1);
    COMPUTE(cur);
    // t+1's 8 loads were issued ~2.5K cycles ago (full MFMA phase) -> done.
    asm volatile("s_waitcnt vmcnt(0)" ::: "memory");
    __builtin_amdgcn_s_barrier();
    __builtin_amdgcn_sched_barrier(0);
    cur ^= 1;
  }
  COMPUTE(cur);  // tile 11

  const int zz = n0p / 768;          // uniform per block
  const int nbase = n0p - zz * 768;  // local n within z

  if (zz < 2) {
    unsigned short* O = (zz == 0) ? O0 : O1;
    const float* bias = (zz == 0) ? b0 : b1;
    const float osc = (zz == 0) ? 0.18033688f : 1.0f;  // log2(e)/sqrt(64) into Q
#pragma unroll
    for (int ni = 0; ni < 4; ++ni) {
      const int n = nbase + wn + ni * 16 + col;
      const float bb = bias[n];
#pragma unroll
      for (int mi = 0; mi < 8; ++mi)
#pragma unroll
        for (int r = 0; r < 4; ++r) {
          const int m = m0 + wm + mi * 16 + qd * 4 + r;
          O[(size_t)m * 768 + n] = f2b((acc[mi][ni][r] + bb) * osc);
        }
    }
  } else {
    // V^T via LDS transpose: T[nl][ml] 256x256 ushort (128 KB), m-chunk
    // XOR-swizzled by (nl&31) for conflict-bounded access.
    __syncthreads();  // all waves done with k-loop LDS reads
    unsigned short* T = LDS;
#pragma unroll
    for (int ni = 0; ni < 4; ++ni) {
      const int nl = wn + ni * 16 + col;
      const float bb = b2[nbase + nl];
#pragma unroll
      for (int mi = 0; mi < 8; ++mi) {
        const int ml = wm + mi * 16 + qd * 4;
        const int mc = ml >> 3;
        ushort4 o;
        o.x = f2b(acc[mi][ni][0] + bb);
        o.y = f2b(acc[mi][ni][1] + bb);
        o.z = f2b(acc[mi][ni][2] + bb);
        o.w = f2b(acc[mi][ni][3] + bb);
        *(ushort4*)&T[(nl << 8) + (((mc ^ (nl & 31)) & 31) << 3) + (ml & 7)] = o;
      }
    }
    __syncthreads();
    const int nl2 = t >> 1;        // 0..255
    const int seg = t & 1;         // 0..1 (128 m each)
    const int nglob = nbase + nl2; // 0..767
    const int hh = nglob >> 6, dd = nglob & 63;
    const int bb2 = m0 >> 10;
    unsigned short* dstp =
        &OVT[(((size_t)bb2 * 12 + hh) * 64 + dd) * 1024 + (m0 & 1023) + seg * 128];
#pragma unroll
    for (int j = 0; j < 16; ++j) {
      const int mc = seg * 16 + j;
      uint4 vv = *(const uint4*)&T[(nl2 << 8) + (((mc ^ (nl2 & 31)) & 31) << 3)];
      *(uint4*)&dstp[j * 8] = vv;
    }
  }
#undef STAGE
#undef COMPUTE
}

// Flash attention v7: v6 + T5 setprio around QK and PV MFMA clusters.
__global__ __launch_bounds__(256) void attn(
    const unsigned short* __restrict__ Q, const unsigned short* __restrict__ K,
    const unsigned short* __restrict__ VT, float* __restrict__ O) {
  __shared__ __align__(16) unsigned short Ks0[4096];
  __shared__ __align__(16) unsigned short Ks1[4096];
  __shared__ __align__(16) unsigned short Vt0[4096];
  __shared__ __align__(16) unsigned short Vt1[4096];

  const int g = blockIdx.x;
  const int orig = (g & 7) * 192 + (g >> 3);
  const int qt = orig & 7;
  const int hb = orig >> 3;  // h + 12*b
  const int b = hb / 12;
  const int h = hb - b * 12;

  const int t = threadIdx.x, w = t >> 6, l = t & 63, qd = l >> 4, col = l & 15;
  const size_t bh = (size_t)b * 786432 + (size_t)h * 64;
  const unsigned short* Kb = K + bh;
  const unsigned short* VTb = VT + ((size_t)(b * 12 + h)) * 65536;

  short8 qf[2][2];
  {
    const unsigned short* Qg = Q + bh + (size_t)(qt * 128 + w * 32) * 768;
#pragma unroll
    for (int mi = 0; mi < 2; ++mi)
#pragma unroll
      for (int ks = 0; ks < 2; ++ks)
        qf[mi][ks] =
            *(const short8*)&Qg[(size_t)(mi * 16 + col) * 768 + ks * 32 + qd * 8];
  }

  const int c0 = t, c1 = 256 + t;
  const int r0 = c0 >> 3, cc0 = (c0 ^ r0 ^ (r0 >> 3)) & 7;
  const int r1 = c1 >> 3, cc1 = (c1 ^ r1 ^ (r1 >> 3)) & 7;

#define STAGE_K(ktile, dst)                                             \
  do {                                                                  \
    const unsigned short* Kg_ = Kb + (size_t)(ktile)*49152;             \
    gld16(&Kg_[(size_t)r0 * 768 + cc0 * 8], &dst[c0 * 8]);              \
    gld16(&Kg_[(size_t)r1 * 768 + cc1 * 8], &dst[c1 * 8]);              \
  } while (0)

#define STAGE_V(ktile, dst)                                             \
  do {                                                                  \
    const unsigned short* Vg_ = VTb + (ktile)*64;                       \
    gld16(&Vg_[(size_t)r0 * 1024 + cc0 * 8], &dst[c0 * 8]);             \
    gld16(&Vg_[(size_t)r1 * 1024 + cc1 * 8], &dst[c1 * 8]);             \
  } while (0)

  STAGE_K(0, Ks0);
  STAGE_V(0, Vt0);

  float4v acc[2][4];
  float4v accl[2];
#pragma unroll
  for (int mi = 0; mi < 2; ++mi) {
    accl[mi] = (float4v)0.0f;
#pragma unroll
    for (int dt = 0; dt < 4; ++dt) acc[mi][dt] = (float4v)0.0f;
  }

  short8 ones;
#pragma unroll
  for (int j = 0; j < 8; ++j) ones[j] = (short)0x3F80;  // bf16 1.0

  __syncthreads();

#define ATTN_ITER(kt, KsR, VtR, KsW, VtW)                                 \
  do {                                                                    \
    if ((kt) < 15) {                                                      \
      STAGE_K((kt) + 1, KsW);                                             \
      STAGE_V((kt) + 1, VtW);                                             \
    }                                                                     \
    short8 kf[2][4];                                                      \
    _Pragma("unroll") for (int ks = 0; ks < 2; ++ks)                      \
        _Pragma("unroll") for (int ni = 0; ni < 4; ++ni)                  \
        kf[ks][ni] =                                                      \
        *(const short8*)&KsR[swa(ni * 16 + col, ks * 32 + qd * 8)];       \
    float4v sT[2][4];                                                     \
    _Pragma("unroll") for (int mi = 0; mi < 2; ++mi)                      \
        _Pragma("unroll") for (int ni = 0; ni < 4; ++ni)                  \
        sT[mi][ni] = (float4v)0.0f;                                       \
    __builtin_amdgcn_s_setprio(1);                                        \
    _Pragma("unroll") for (int ks = 0; ks < 2; ++ks)                      \
        _Pragma("unroll") for (int ni = 0; ni < 4; ++ni) {                \
      sT[0][ni] = MFMA_BF16(kf[ks][ni], qf[0][ks], sT[0][ni], 0, 0, 0);   \
      sT[1][ni] = MFMA_BF16(kf[ks][ni], qf[1][ks], sT[1][ni], 0, 0, 0);   \
    }                                                                     \
    __builtin_amdgcn_s_setprio(0);                                        \
    _Pragma("unroll") for (int s = 0; s < 2; ++s) {                       \
      short8 pf[2];                                                       \
      _Pragma("unroll") for (int mi = 0; mi < 2; ++mi) {                  \
        float4v sa = sT[mi][s * 2 + 0];                                   \
        float4v sb = sT[mi][s * 2 + 1];                                   \
        unsigned A0 = pk2(__builtin_amdgcn_exp2f(sa[0]),                  \
                          __builtin_amdgcn_exp2f(sa[1]));                 \
        unsigned A1 = pk2(__builtin_amdgcn_exp2f(sa[2]),                  \
                          __builtin_amdgcn_exp2f(sa[3]));                 \
        unsigned B0 = pk2(__builtin_amdgcn_exp2f(sb[0]),                  \
                          __builtin_amdgcn_exp2f(sb[1]));                 \
        unsigned B1 = pk2(__builtin_amdgcn_exp2f(sb[2]),                  \
                          __builtin_amdgcn_exp2f(sb[3]));                 \
        uint2v x0 = __builtin_amdgcn_permlane32_swap(A0, B0, false, false);   \
        uint2v x1 = __builtin_amdgcn_permlane32_swap(A1, B1, false, false);   \
        uint2v y02 = __builtin_amdgcn_permlane16_swap(x0[0], x0[1], false, false); \
        uint2v y13 = __builtin_amdgcn_permlane16_swap(x1[0], x1[1], false, false); \
        union { unsigned u[4]; short8 v; } pu;                            \
        pu.u[0] = y02[0]; pu.u[1] = y13[0];                               \
        pu.u[2] = y02[1]; pu.u[3] = y13[1];                               \
        pf[mi] = pu.v;                                                    \
      }                                                                   \
      const int kk = s * 32 + qd * 8;                                     \
      __builtin_amdgcn_s_setprio(1);                                      \
      _Pragma("unroll") for (int dt = 0; dt < 4; ++dt) {                  \
        short8 vf = *(const short8*)&VtR[swa(dt * 16 + col, kk)];         \
        acc[0][dt] = MFMA_BF16(vf, pf[0], acc[0][dt], 0, 0, 0);           \
        acc[1][dt] = MFMA_BF16(vf, pf[1], acc[1][dt], 0, 0, 0);           \
      }                                                                   \
      accl[0] = MFMA_BF16(ones, pf[0], accl[0], 0, 0, 0);                 \
      accl[1] = MFMA_BF16(ones, pf[1], accl[1], 0, 0, 0);                 \
      __builtin_amdgcn_s_setprio(0);                                      \
    }                                                                     \
    __syncthreads();                                                      \
  } while (0)

  for (int kt2 = 0; kt2 < 16; kt2 += 2) {
    ATTN_ITER(kt2, Ks0, Vt0, Ks1, Vt1);
    ATTN_ITER(kt2 + 1, Ks1, Vt1, Ks0, Vt0);
  }

  float* Og = O + (size_t)(b * 1024 + qt * 128) * 768 + h * 64;
#pragma unroll
  for (int mi = 0; mi < 2; ++mi) {
    const float rl = 1.0f / accl[mi][0];
    const int q = w * 32 + mi * 16 + col;
#pragma unroll
    for (int dt = 0; dt < 4; ++dt) {
      float4 o;
      o.x = acc[mi][dt][0] * rl;
      o.y = acc[mi][dt][1] * rl;
      o.z = acc[mi][dt][2] * rl;
      o.w = acc[mi][dt][3] * rl;
      *(float4*)&Og[(size_t)q * 768 + dt * 16 + qd * 4] = o;
    }
  }
#undef STAGE_K
#undef STAGE_V
#undef ATTN_ITER
}

extern "C" void kernel_launch(void* const* d_in, const int* in_sizes, int n_in,
                              void* d_out, int out_size, void* d_ws, size_t ws_size,
                              hipStream_t stream) {
  const float* hs = (const float*)d_in[0];
  const float* Wq = (const float*)d_in[1];
  const float* bq = (const float*)d_in[2];
  const float* Wk = (const float*)d_in[3];
  const float* bk = (const float*)d_in[4];
  const float* Wv = (const float*)d_in[5];
  const float* bv = (const float*)d_in[6];
  float* out = (float*)d_out;
  char* ws = (char*)d_ws;

  unsigned short* Xb = (unsigned short*)ws;
  unsigned short* Wb = (unsigned short*)(ws + 25165824);
  unsigned short* Qb = (unsigned short*)(ws + 28704768);
  unsigned short* Kb = (unsigned short*)(ws + 53870592);
  unsigned short* Vb = (unsigned short*)(ws + 79036416);  // V^T [b][h][d][s]

  static bool attr_set = false;
  if (!attr_set) {
    hipFuncSetAttribute((const void*)qkv_gemm,
                        hipFuncAttributeMaxDynamicSharedMemorySize, 131072);
    attr_set = true;
  }

  cast_all<<<14016, 256, 0, stream>>>(hs, Wq, Wk, Wv, Xb, Wb);

  qkv_gemm<<<dim3(576), 512, 131072, stream>>>(Xb, Wb, bq, bk, bv, Qb, Kb, Vb);

  attn<<<dim3(1536), 256, 0, stream>>>(Qb, Kb, Vb, out);
}